// Round 2
// baseline (183.845 us; speedup 1.0000x reference)
//
#include <hip/hip_runtime.h>

typedef short short8  __attribute__((ext_vector_type(8)));
typedef short short4v __attribute__((ext_vector_type(4)));
typedef float f32x4   __attribute__((ext_vector_type(4)));

__device__ __forceinline__ unsigned short f2bf(float f) {
  unsigned int u = __builtin_bit_cast(unsigned int, f);
  u += 0x7fffu + ((u >> 16) & 1u);   // RNE
  return (unsigned short)(u >> 16);
}

// ---------------------------------------------------------------------------
// Kernel 1: QKV projection.  x:[B=4][C=64][N=4096] f32.
// q,k -> bf16 [b][n][16] (row-contiguous, MFMA A-frag friendly); v -> bf16
// [b][c][n].  One lane per n-column; x column cached in 64 VGPRs; weight rows
// are wave-uniform pointers -> scalar loads on the s-pipe.
// ---------------------------------------------------------------------------
__global__ __launch_bounds__(256) void qkv_proj(
    const float* __restrict__ x,
    const float* __restrict__ Wq, const float* __restrict__ bq,
    const float* __restrict__ Wk, const float* __restrict__ bk,
    const float* __restrict__ Wv, const float* __restrict__ bv,
    unsigned short* __restrict__ qb, unsigned short* __restrict__ kb,
    unsigned short* __restrict__ vb)
{
  const int b    = blockIdx.x >> 6;
  const int n0   = (blockIdx.x & 63) << 6;
  const int wave = threadIdx.x >> 6;
  const int lane = threadIdx.x & 63;
  const int n    = n0 + lane;

  float xc[64];
#pragma unroll
  for (int c = 0; c < 64; ++c)
    xc[c] = x[((size_t)(b * 64 + c)) * 4096 + n];

  const int og0 = __builtin_amdgcn_readfirstlane(wave * 24);
  for (int i = 0; i < 24; ++i) {
    const int og = og0 + i;
    const float* wrow;
    float acc;
    if (og < 16)      { wrow = Wq + og * 64;        acc = bq[og]; }
    else if (og < 32) { wrow = Wk + (og - 16) * 64; acc = bk[og - 16]; }
    else              { wrow = Wv + (og - 32) * 64; acc = bv[og - 32]; }
#pragma unroll
    for (int c = 0; c < 64; ++c)
      acc += wrow[c] * xc[c];
    unsigned short r = f2bf(acc);
    if (og < 16)      qb[(((size_t)b * 4096 + n) * 16) + og]        = r;
    else if (og < 32) kb[(((size_t)b * 4096 + n) * 16) + (og - 16)] = r;
    else              vb[((size_t)(b * 64 + (og - 32))) * 4096 + n] = r;
  }
}

// ---------------------------------------------------------------------------
// Kernel 2: fused flash attention (no-max softmax; shift-invariance + |S|<~5
// makes exp(S) safe in f32).  One block = (b, 64-query tile), 4 waves, each
// wave owns 16 query rows via mfma_f32_16x16x32_bf16 (k padded 16->32 w/ 0s).
// P crosses C-layout -> A-layout through per-wave LDS [sub][i][16+4 pad].
// ---------------------------------------------------------------------------
__global__ __launch_bounds__(256) void flash_attn(
    const unsigned short* __restrict__ qb, const unsigned short* __restrict__ kb,
    const unsigned short* __restrict__ vb, const float* __restrict__ x,
    const float* __restrict__ gptr, float* __restrict__ out)
{
  __shared__ unsigned short k_lds[64 * 16];        // [j][16]
  __shared__ unsigned short v_lds[64 * 72];        // [c][64+8 pad]
  __shared__ unsigned short p_lds[4][4 * 16 * 20]; // per-wave [sub][i][16+4 pad]

  const int b    = blockIdx.x >> 6;
  const int q0   = (blockIdx.x & 63) << 6;
  const int t    = threadIdx.x;
  const int wave = t >> 6;
  const int lane = t & 63;
  const int l15  = lane & 15;
  const int quad = lane >> 4;

  // Q A-fragment: m=l15 -> query q0+wave*16+l15, k=quad*8+jj -> channel.
  short8 qfrag = (short8)0;
  if (quad < 2) {
    const int iq = q0 + wave * 16 + l15;
    qfrag = *(const short8*)(qb + (((size_t)b * 4096 + iq) * 16 + quad * 8));
  }

  f32x4 acc0 = (f32x4)0.f, acc1 = (f32x4)0.f, acc2 = (f32x4)0.f, acc3 = (f32x4)0.f;
  float lp0 = 0.f, lp1 = 0.f, lp2 = 0.f, lp3 = 0.f;
  unsigned short* pw = &p_lds[wave][0];

  for (int j0 = 0; j0 < 4096; j0 += 64) {
    __syncthreads();                                  // prev iter reads done
    if (t < 128)                                      // K tile: 2 KB contiguous
      *(short8*)(k_lds + t * 8) =
          *(const short8*)(kb + ((size_t)b * 4096 + j0) * 16 + t * 8);
    {                                                 // V tile: 64 rows x 128B
      int c = t >> 3, col = (t & 7) * 8;
      *(short8*)(v_lds + c * 72 + col) =
          *(const short8*)(vb + ((size_t)(b * 64 + c)) * 4096 + j0 + col);
      c += 32;
      *(short8*)(v_lds + c * 72 + col) =
          *(const short8*)(vb + ((size_t)(b * 64 + c)) * 4096 + j0 + col);
    }
    __syncthreads();                                  // staging visible

    // S = Q K^T for 4 sub-tiles of 16 keys, then P = exp(S) -> LDS (bf16)
#pragma unroll
    for (int sub = 0; sub < 4; ++sub) {
      short8 kf = (short8)0;
      if (quad < 2)
        kf = *(const short8*)(k_lds + (sub * 16 + l15) * 16 + quad * 8);
      f32x4 s = __builtin_amdgcn_mfma_f32_16x16x32_bf16(qfrag, kf, (f32x4)0.f, 0, 0, 0);
      float p0 = __expf(s[0]); lp0 += p0;
      float p1 = __expf(s[1]); lp1 += p1;
      float p2 = __expf(s[2]); lp2 += p2;
      float p3 = __expf(s[3]); lp3 += p3;
      const int base = sub * 16 + quad * 4;           // row=sub*16+i, col=l15
      pw[(base + 0) * 20 + l15] = f2bf(p0);
      pw[(base + 1) * 20 + l15] = f2bf(p1);
      pw[(base + 2) * 20 + l15] = f2bf(p2);
      pw[(base + 3) * 20 + l15] = f2bf(p3);
    }
    __syncthreads();                                  // drain P writes

    // O += P V  (A = P from LDS in A-layout, B = V rows from v_lds)
#pragma unroll
    for (int kc = 0; kc < 2; ++kc) {
      const int pi = ((kc * 2 + (quad >> 1)) * 16 + l15) * 20 + (quad & 1) * 8;
      short4v plo = *(const short4v*)(pw + pi);
      short4v phi = *(const short4v*)(pw + pi + 4);
      short8 pf;
      pf[0] = plo[0]; pf[1] = plo[1]; pf[2] = plo[2]; pf[3] = plo[3];
      pf[4] = phi[0]; pf[5] = phi[1]; pf[6] = phi[2]; pf[7] = phi[3];
      const int vcol = kc * 32 + quad * 8;
      short8 vf0 = *(const short8*)(v_lds + (0 * 16 + l15) * 72 + vcol);
      acc0 = __builtin_amdgcn_mfma_f32_16x16x32_bf16(pf, vf0, acc0, 0, 0, 0);
      short8 vf1 = *(const short8*)(v_lds + (1 * 16 + l15) * 72 + vcol);
      acc1 = __builtin_amdgcn_mfma_f32_16x16x32_bf16(pf, vf1, acc1, 0, 0, 0);
      short8 vf2 = *(const short8*)(v_lds + (2 * 16 + l15) * 72 + vcol);
      acc2 = __builtin_amdgcn_mfma_f32_16x16x32_bf16(pf, vf2, acc2, 0, 0, 0);
      short8 vf3 = *(const short8*)(v_lds + (3 * 16 + l15) * 72 + vcol);
      acc3 = __builtin_amdgcn_mfma_f32_16x16x32_bf16(pf, vf3, acc3, 0, 0, 0);
    }
  }

  // row sums: reduce over the 16 key-lanes (xor masks stay inside the quad)
#pragma unroll
  for (int m = 1; m < 16; m <<= 1) {
    lp0 += __shfl_xor(lp0, m);
    lp1 += __shfl_xor(lp1, m);
    lp2 += __shfl_xor(lp2, m);
    lp3 += __shfl_xor(lp3, m);
  }
  const float g = gptr[0];
  const float li[4] = {1.f / lp0, 1.f / lp1, 1.f / lp2, 1.f / lp3};
  const int posb = q0 + wave * 16 + quad * 4;

  f32x4 accs[4] = {acc0, acc1, acc2, acc3};
#pragma unroll
  for (int ct = 0; ct < 4; ++ct) {
    const int c = ct * 16 + l15;
#pragma unroll
    for (int r = 0; r < 4; ++r) {
      const size_t off = ((size_t)(b * 64 + c)) * 4096 + (posb + r);
      out[off] = g * (accs[ct][r] * li[r]) + x[off];
    }
  }
}

// ---------------------------------------------------------------------------
extern "C" void kernel_launch(void* const* d_in, const int* in_sizes, int n_in,
                              void* d_out, int out_size, void* d_ws, size_t ws_size,
                              hipStream_t stream)
{
  const float* x  = (const float*)d_in[0];
  const float* Wq = (const float*)d_in[1];
  const float* bq = (const float*)d_in[2];
  const float* Wk = (const float*)d_in[3];
  const float* bk = (const float*)d_in[4];
  const float* Wv = (const float*)d_in[5];
  const float* bv = (const float*)d_in[6];
  const float* g  = (const float*)d_in[7];

  unsigned short* ws = (unsigned short*)d_ws;
  unsigned short* qb = ws;                 // 4*4096*16 bf16
  unsigned short* kb = ws + 262144;        // 4*4096*16 bf16
  unsigned short* vb = ws + 524288;        // 4*64*4096 bf16
  float* ob = (float*)d_out;

  hipLaunchKernelGGL(qkv_proj, dim3(256), dim3(256), 0, stream,
                     x, Wq, bq, Wk, bk, Wv, bv, qb, kb, vb);
  hipLaunchKernelGGL(flash_attn, dim3(256), dim3(256), 0, stream,
                     qb, kb, vb, x, g, ob);
}

// Round 3
// 128.415 us; speedup vs baseline: 1.4316x; 1.4316x over previous
//
#include <hip/hip_runtime.h>

typedef short short8  __attribute__((ext_vector_type(8)));
typedef short short4v __attribute__((ext_vector_type(4)));
typedef float f32x4   __attribute__((ext_vector_type(4)));

__device__ __forceinline__ unsigned short f2bf(float f) {
  unsigned int u = __builtin_bit_cast(unsigned int, f);
  u += 0x7fffu + ((u >> 16) & 1u);   // RNE
  return (unsigned short)(u >> 16);
}

// ---------------------------------------------------------------------------
// Kernel 1: QKV projection as straight-line MFMA GEMM: C[96,N] = W[96,64]*X[64,N]+b.
// No LDS, no barriers, no scalar-load dependence. Grid 512 = b(4) x ntile(64) x
// rowhalf(2); block = 4 waves, wave = one 16-col tile of n; each wave does 3
// row-tiles x 2 K-steps of mfma_f32_16x16x32_bf16.
// A-frag: A[m=l15][k=quad*8+jj] = W[row][c];  B-frag: B[k][n=l15] = x[c][n].
// Q,K stored [b][n][16] bf16 (8B short4 stores, = flash's A-frag layout);
// V stored [b][c][n] bf16.
// ---------------------------------------------------------------------------
__global__ __launch_bounds__(256) void qkv_mfma(
    const float* __restrict__ x,
    const float* __restrict__ Wq, const float* __restrict__ bq,
    const float* __restrict__ Wk, const float* __restrict__ bk,
    const float* __restrict__ Wv, const float* __restrict__ bv,
    unsigned short* __restrict__ qb, unsigned short* __restrict__ kb,
    unsigned short* __restrict__ vb)
{
  const int bid  = blockIdx.x;
  const int rh   = bid & 1;
  const int nt   = (bid >> 1) & 63;
  const int b    = bid >> 7;
  const int lane = threadIdx.x & 63;
  const int wave = threadIdx.x >> 6;
  const int l15  = lane & 15;
  const int quad = lane >> 4;
  const int n    = nt * 64 + wave * 16 + l15;

  // B-frags (x columns), shared across the 3 row-tiles.
  short8 bfrag[2];
#pragma unroll
  for (int ks = 0; ks < 2; ++ks)
#pragma unroll
    for (int jj = 0; jj < 8; ++jj) {
      const int c = ks * 32 + quad * 8 + jj;
      bfrag[ks][jj] = (short)f2bf(x[((size_t)(b * 64 + c)) * 4096 + n]);
    }

#pragma unroll
  for (int rti = 0; rti < 3; ++rti) {
    const int rt = rh * 3 + rti;          // row-tile 0..5 (uniform per block)
    const float* wbase; const float* bias; int row0;
    if (rt == 0)      { wbase = Wq; bias = bq; row0 = 0; }
    else if (rt == 1) { wbase = Wk; bias = bk; row0 = 0; }
    else              { wbase = Wv; bias = bv; row0 = (rt - 2) * 16; }

    short8 afrag[2];
#pragma unroll
    for (int ks = 0; ks < 2; ++ks)
#pragma unroll
      for (int jj = 0; jj < 8; ++jj)
        afrag[ks][jj] = (short)f2bf(wbase[(row0 + l15) * 64 + ks * 32 + quad * 8 + jj]);

    f32x4 acc;
#pragma unroll
    for (int r = 0; r < 4; ++r)
      acc[r] = bias[row0 + quad * 4 + r];
    acc = __builtin_amdgcn_mfma_f32_16x16x32_bf16(afrag[0], bfrag[0], acc, 0, 0, 0);
    acc = __builtin_amdgcn_mfma_f32_16x16x32_bf16(afrag[1], bfrag[1], acc, 0, 0, 0);

    // C[row=quad*4+r][col=n(l15)]
    if (rt <= 1) {
      short4v sv;
#pragma unroll
      for (int r = 0; r < 4; ++r) sv[r] = (short)f2bf(acc[r]);
      unsigned short* dst = (rt == 0 ? qb : kb);
      *(short4v*)(dst + (((size_t)b * 4096 + n) * 16) + quad * 4) = sv;
    } else {
#pragma unroll
      for (int r = 0; r < 4; ++r) {
        const int c = (rt - 2) * 16 + quad * 4 + r;
        vb[((size_t)(b * 64 + c)) * 4096 + n] = f2bf(acc[r]);
      }
    }
  }
}

// ---------------------------------------------------------------------------
// Kernel 2: flash attention partials with j-split=4 (no-max softmax is linear
// in j, so O/l partials are exactly additive).  Grid 1024 = b(4) x qtile(64) x
// split(4) -> 4 blocks/CU.  Each block: 16 j-iterations over its 1024-key range.
// Writes f32 O-partial [64c][64q] and l-partial [64q] per (b,qtile,split).
// ---------------------------------------------------------------------------
__global__ __launch_bounds__(256) void flash_attn(
    const unsigned short* __restrict__ qb, const unsigned short* __restrict__ kb,
    const unsigned short* __restrict__ vb,
    float* __restrict__ Opart, float* __restrict__ lpart)
{
  __shared__ unsigned short k_lds[64 * 16];        // [j][16]
  __shared__ unsigned short v_lds[64 * 72];        // [c][64+8 pad]
  __shared__ unsigned short p_lds[4][4 * 16 * 20]; // per-wave [sub][i][16+4 pad]

  const int bid  = blockIdx.x;
  const int s    = bid & 3;
  const int qt   = (bid >> 2) & 63;
  const int b    = bid >> 8;
  const int q0   = qt * 64;
  const int t    = threadIdx.x;
  const int wave = t >> 6;
  const int lane = t & 63;
  const int l15  = lane & 15;
  const int quad = lane >> 4;

  short8 qfrag = (short8)0;
  if (quad < 2) {
    const int iq = q0 + wave * 16 + l15;
    qfrag = *(const short8*)(qb + (((size_t)b * 4096 + iq) * 16 + quad * 8));
  }

  f32x4 acc0 = (f32x4)0.f, acc1 = (f32x4)0.f, acc2 = (f32x4)0.f, acc3 = (f32x4)0.f;
  float lp0 = 0.f, lp1 = 0.f, lp2 = 0.f, lp3 = 0.f;
  unsigned short* pw = &p_lds[wave][0];

  const int jbeg = s * 1024;
  for (int j0 = jbeg; j0 < jbeg + 1024; j0 += 64) {
    __syncthreads();
    if (t < 128)
      *(short8*)(k_lds + t * 8) =
          *(const short8*)(kb + ((size_t)b * 4096 + j0) * 16 + t * 8);
    {
      int c = t >> 3, col = (t & 7) * 8;
      *(short8*)(v_lds + c * 72 + col) =
          *(const short8*)(vb + ((size_t)(b * 64 + c)) * 4096 + j0 + col);
      c += 32;
      *(short8*)(v_lds + c * 72 + col) =
          *(const short8*)(vb + ((size_t)(b * 64 + c)) * 4096 + j0 + col);
    }
    __syncthreads();

#pragma unroll
    for (int sub = 0; sub < 4; ++sub) {
      short8 kf = (short8)0;
      if (quad < 2)
        kf = *(const short8*)(k_lds + (sub * 16 + l15) * 16 + quad * 8);
      f32x4 sc = __builtin_amdgcn_mfma_f32_16x16x32_bf16(qfrag, kf, (f32x4)0.f, 0, 0, 0);
      float p0 = __expf(sc[0]); lp0 += p0;
      float p1 = __expf(sc[1]); lp1 += p1;
      float p2 = __expf(sc[2]); lp2 += p2;
      float p3 = __expf(sc[3]); lp3 += p3;
      const int base = sub * 16 + quad * 4;
      pw[(base + 0) * 20 + l15] = f2bf(p0);
      pw[(base + 1) * 20 + l15] = f2bf(p1);
      pw[(base + 2) * 20 + l15] = f2bf(p2);
      pw[(base + 3) * 20 + l15] = f2bf(p3);
    }
    __syncthreads();

#pragma unroll
    for (int kc = 0; kc < 2; ++kc) {
      const int pi = ((kc * 2 + (quad >> 1)) * 16 + l15) * 20 + (quad & 1) * 8;
      short4v plo = *(const short4v*)(pw + pi);
      short4v phi = *(const short4v*)(pw + pi + 4);
      short8 pf;
      pf[0] = plo[0]; pf[1] = plo[1]; pf[2] = plo[2]; pf[3] = plo[3];
      pf[4] = phi[0]; pf[5] = phi[1]; pf[6] = phi[2]; pf[7] = phi[3];
      const int vcol = kc * 32 + quad * 8;
      short8 vf0 = *(const short8*)(v_lds + (0 * 16 + l15) * 72 + vcol);
      acc0 = __builtin_amdgcn_mfma_f32_16x16x32_bf16(pf, vf0, acc0, 0, 0, 0);
      short8 vf1 = *(const short8*)(v_lds + (1 * 16 + l15) * 72 + vcol);
      acc1 = __builtin_amdgcn_mfma_f32_16x16x32_bf16(pf, vf1, acc1, 0, 0, 0);
      short8 vf2 = *(const short8*)(v_lds + (2 * 16 + l15) * 72 + vcol);
      acc2 = __builtin_amdgcn_mfma_f32_16x16x32_bf16(pf, vf2, acc2, 0, 0, 0);
      short8 vf3 = *(const short8*)(v_lds + (3 * 16 + l15) * 72 + vcol);
      acc3 = __builtin_amdgcn_mfma_f32_16x16x32_bf16(pf, vf3, acc3, 0, 0, 0);
    }
  }

#pragma unroll
  for (int m = 1; m < 16; m <<= 1) {
    lp0 += __shfl_xor(lp0, m);
    lp1 += __shfl_xor(lp1, m);
    lp2 += __shfl_xor(lp2, m);
    lp3 += __shfl_xor(lp3, m);
  }

  const int pslot = (b * 64 + qt) * 4 + s;
  const int posb  = wave * 16 + quad * 4;
  float* Op = Opart + (size_t)pslot * 4096;
  f32x4 accs[4] = {acc0, acc1, acc2, acc3};
#pragma unroll
  for (int ct = 0; ct < 4; ++ct)
    *(f32x4*)(Op + (ct * 16 + l15) * 64 + posb) = accs[ct];   // [c][q]
  if (l15 == 0) {
    f32x4 lv; lv[0] = lp0; lv[1] = lp1; lv[2] = lp2; lv[3] = lp3;
    *(f32x4*)(lpart + (size_t)pslot * 64 + posb) = lv;
  }
}

// ---------------------------------------------------------------------------
// Kernel 3: combine splits, normalize, gamma*O + x.  Grid 256 = (b, qtile).
// ---------------------------------------------------------------------------
__global__ __launch_bounds__(256) void finalize(
    const float* __restrict__ Opart, const float* __restrict__ lpart,
    const float* __restrict__ x, const float* __restrict__ gptr,
    float* __restrict__ out)
{
  __shared__ float linv[64];
  const int b  = blockIdx.x >> 6;
  const int qt = blockIdx.x & 63;
  const int t  = threadIdx.x;
  const int base = (b * 64 + qt) * 4;

  if (t < 64) {
    float sum = 0.f;
#pragma unroll
    for (int s = 0; s < 4; ++s) sum += lpart[(size_t)(base + s) * 64 + t];
    linv[t] = 1.f / sum;
  }
  __syncthreads();

  const int q  = t & 63;
  const int cg = t >> 6;
  const float g  = gptr[0];
  const float li = linv[q];
#pragma unroll
  for (int i = 0; i < 16; ++i) {
    const int c = cg * 16 + i;
    float o = 0.f;
#pragma unroll
    for (int s = 0; s < 4; ++s)
      o += Opart[(size_t)(base + s) * 4096 + c * 64 + q];
    const size_t off = ((size_t)(b * 64 + c)) * 4096 + qt * 64 + q;
    out[off] = g * (o * li) + x[off];
  }
}

// ---------------------------------------------------------------------------
extern "C" void kernel_launch(void* const* d_in, const int* in_sizes, int n_in,
                              void* d_out, int out_size, void* d_ws, size_t ws_size,
                              hipStream_t stream)
{
  const float* x  = (const float*)d_in[0];
  const float* Wq = (const float*)d_in[1];
  const float* bq = (const float*)d_in[2];
  const float* Wk = (const float*)d_in[3];
  const float* bk = (const float*)d_in[4];
  const float* Wv = (const float*)d_in[5];
  const float* bv = (const float*)d_in[6];
  const float* g  = (const float*)d_in[7];

  unsigned short* ws = (unsigned short*)d_ws;
  unsigned short* qb = ws;                 // 262144 bf16
  unsigned short* kb = ws + 262144;        // 262144 bf16
  unsigned short* vb = ws + 524288;        // 1048576 bf16
  float* Opart = (float*)((char*)d_ws + 3145728);   // 4*64*4*4096 f32 = 16 MB
  float* lpart = (float*)((char*)d_ws + 19922944);  // 4*64*4*64 f32 = 256 KB
  float* ob = (float*)d_out;

  hipLaunchKernelGGL(qkv_mfma, dim3(512), dim3(256), 0, stream,
                     x, Wq, bq, Wk, bk, Wv, bv, qb, kb, vb);
  hipLaunchKernelGGL(flash_attn, dim3(1024), dim3(256), 0, stream,
                     qb, kb, vb, Opart, lpart);
  hipLaunchKernelGGL(finalize, dim3(256), dim3(256), 0, stream,
                     Opart, lpart, x, g, ob);
}